// Round 14
// baseline (625.703 us; speedup 1.0000x reference)
//
#include <hip/hip_runtime.h>
#include <float.h>

// VectorQuantizer: N=262144 rows of D=64 fp32, K=1024 codebook rows.
// out = [x_quantized (N*D f32) | embed_inds (N, written as f32)]
//
// Bit-exact np-fp32 semantics (verified R4): score = fmaf(-2, seq-dot,
// fadd(xnorm, enorm)); pairwise-8 norms; strict < ascending k (first-min).
//
// R14: cb row -> SGPRs via explicit s_load_dwordx16 x4 (wave-uniform operand
// on the SCALAR pipe). k-loop has zero LDS / zero VMEM: v_fma takes the SGPR
// operand directly. x-row in 16 named float4 VGPRs. waves_per_eu(4,4):
// budget 128 (no spill), no remat incentive (max==min), 4 waves/SIMD == grid
// -> 3 sibling waves hide the ~200-300cyc scalar-cache/L2 latency per k.
// R12/R13 showed LDS-pipe co-limitation and a hard 128-VGPR toolchain cap;
// this moves the broadcast operand off both contested pipes.

typedef __attribute__((ext_vector_type(16))) float f32x16;

static constexpr int D_DIM = 64;
static constexpr int K_CB  = 1024;
static constexpr int TPB   = 256;      // 4 waves/block; grid 1024 -> 4 waves/SIMD

// numpy pairwise-8 sum of squares of 64 values held as 16 float4s.
#define NP_INIT(c0, c1)                                                     \
    float ax = __fmul_rn(c0.x, c0.x), ay = __fmul_rn(c0.y, c0.y),           \
          az = __fmul_rn(c0.z, c0.z), aw = __fmul_rn(c0.w, c0.w);           \
    float bx = __fmul_rn(c1.x, c1.x), by = __fmul_rn(c1.y, c1.y),           \
          bz = __fmul_rn(c1.z, c1.z), bw = __fmul_rn(c1.w, c1.w);
#define NP_ACC(ce, co)                                                      \
    ax = __fadd_rn(ax, __fmul_rn(ce.x, ce.x));                              \
    ay = __fadd_rn(ay, __fmul_rn(ce.y, ce.y));                              \
    az = __fadd_rn(az, __fmul_rn(ce.z, ce.z));                              \
    aw = __fadd_rn(aw, __fmul_rn(ce.w, ce.w));                              \
    bx = __fadd_rn(bx, __fmul_rn(co.x, co.x));                              \
    by = __fadd_rn(by, __fmul_rn(co.y, co.y));                              \
    bz = __fadd_rn(bz, __fmul_rn(co.z, co.z));                              \
    bw = __fadd_rn(bw, __fmul_rn(co.w, co.w));
#define NP_TREE()                                                           \
    __fadd_rn(__fadd_rn(__fadd_rn(ax, ay), __fadd_rn(az, aw)),              \
              __fadd_rn(__fadd_rn(bx, by), __fadd_rn(bz, bw)))

__device__ __forceinline__ float np_pair_sq16(
        float4 c0, float4 c1, float4 c2, float4 c3,
        float4 c4, float4 c5, float4 c6, float4 c7,
        float4 c8, float4 c9, float4 c10, float4 c11,
        float4 c12, float4 c13, float4 c14, float4 c15) {
    NP_INIT(c0, c1)
    NP_ACC(c2, c3)  NP_ACC(c4, c5)  NP_ACC(c6, c7)
    NP_ACC(c8, c9)  NP_ACC(c10, c11) NP_ACC(c12, c13) NP_ACC(c14, c15)
    return NP_TREE();
}

// 16 steps of the d-ascending sequential FMA chain, cb from SGPR vector sv.
#define FMA16(sv, xa, xb, xc, xd)                                           \
    d = __fmaf_rn(sv[0],  xa.x, d); d = __fmaf_rn(sv[1],  xa.y, d);         \
    d = __fmaf_rn(sv[2],  xa.z, d); d = __fmaf_rn(sv[3],  xa.w, d);         \
    d = __fmaf_rn(sv[4],  xb.x, d); d = __fmaf_rn(sv[5],  xb.y, d);         \
    d = __fmaf_rn(sv[6],  xb.z, d); d = __fmaf_rn(sv[7],  xb.w, d);         \
    d = __fmaf_rn(sv[8],  xc.x, d); d = __fmaf_rn(sv[9],  xc.y, d);         \
    d = __fmaf_rn(sv[10], xc.z, d); d = __fmaf_rn(sv[11], xc.w, d);         \
    d = __fmaf_rn(sv[12], xd.x, d); d = __fmaf_rn(sv[13], xd.y, d);         \
    d = __fmaf_rn(sv[14], xd.z, d); d = __fmaf_rn(sv[15], xd.w, d);

__global__ void __launch_bounds__(TPB)
__attribute__((amdgpu_waves_per_eu(4, 4)))
vq_kernel(
        const float* __restrict__ x, const float* __restrict__ cb,
        float* __restrict__ out_q, float* __restrict__ out_idx) {
    __shared__ float es[K_CB];     // 4 KB
    __shared__ int bks[TPB];       // 1 KB

    const int tid = threadIdx.x;
    const size_t row0 = (size_t)blockIdx.x * TPB;
    const size_t row  = row0 + tid;
    const float4* cb4 = reinterpret_cast<const float4*>(cb);

    // ---- phase A: block-local e-norms (numpy pairwise order) ----
#pragma unroll
    for (int j = 0; j < K_CB / TPB; ++j) {
        const int k = tid + TPB * j;
        const float4* cr = cb4 + (size_t)k * 16;
        float4 c0 = cr[0],  c1 = cr[1],  c2 = cr[2],  c3 = cr[3],
               c4 = cr[4],  c5 = cr[5],  c6 = cr[6],  c7 = cr[7],
               c8 = cr[8],  c9 = cr[9],  c10 = cr[10], c11 = cr[11],
               c12 = cr[12], c13 = cr[13], c14 = cr[14], c15 = cr[15];
        es[k] = np_pair_sq16(c0, c1, c2, c3, c4, c5, c6, c7,
                             c8, c9, c10, c11, c12, c13, c14, c15);
    }
    __syncthreads();

    // ---- phase B: my row in 16 NAMED float4 registers; x_norm ----
    const float4* xg = reinterpret_cast<const float4*>(x + row * D_DIM);
    float4 x0 = xg[0],  x1 = xg[1],  x2 = xg[2],  x3 = xg[3],
           x4 = xg[4],  x5 = xg[5],  x6 = xg[6],  x7 = xg[7],
           x8 = xg[8],  x9 = xg[9],  x10 = xg[10], x11 = xg[11],
           x12 = xg[12], x13 = xg[13], x14 = xg[14], x15 = xg[15];
    const float xn = np_pair_sq16(x0, x1, x2, x3, x4, x5, x6, x7,
                                  x8, x9, x10, x11, x12, x13, x14, x15);

    // ---- phase C: k-scan; cb row in SGPRs (scalar pipe), zero LDS/VMEM ----
    float best = FLT_MAX;
    int bestk = 0;
    unsigned long long cbp = (unsigned long long)cb;   // uniform byte address
#pragma unroll 1
    for (int k = 0; k < K_CB; ++k) {
        f32x16 c0_, c1_, c2_, c3_;
        asm volatile(
            "s_load_dwordx16 %0, %4, 0x0\n\t"
            "s_load_dwordx16 %1, %4, 0x40\n\t"
            "s_load_dwordx16 %2, %4, 0x80\n\t"
            "s_load_dwordx16 %3, %4, 0xc0\n\t"
            "s_waitcnt lgkmcnt(0)"
            : "=s"(c0_), "=s"(c1_), "=s"(c2_), "=s"(c3_)
            : "s"(cbp));
        float d = 0.f;
        FMA16(c0_, x0,  x1,  x2,  x3)
        FMA16(c1_, x4,  x5,  x6,  x7)
        FMA16(c2_, x8,  x9,  x10, x11)
        FMA16(c3_, x12, x13, x14, x15)
        const float s = __fmaf_rn(-2.f, d, __fadd_rn(xn, es[k]));
        if (s < best) { best = s; bestk = k; }   // strict < = first-min
        cbp += 4ull * D_DIM;                     // next row (scalar add)
    }

    bks[tid] = bestk;
    __syncthreads();

    // ---- phase D: coalesced gather-write of x_quantized ----
    float4* oq = reinterpret_cast<float4*>(out_q + row0 * D_DIM);
#pragma unroll
    for (int j = 0; j < 16; ++j) {
        const int f = tid + TPB * j;     // 0..4095
        const int r = f >> 4, c = f & 15;
        oq[f] = cb4[(size_t)bks[r] * 16 + c];
    }
    out_idx[row] = (float)bestk;
}

extern "C" void kernel_launch(void* const* d_in, const int* in_sizes, int n_in,
                              void* d_out, int out_size, void* d_ws, size_t ws_size,
                              hipStream_t stream) {
    const float* x  = (const float*)d_in[0];
    const float* cb = (const float*)d_in[1];
    const int n_rows = in_sizes[0] / D_DIM;     // 262144

    float* out_q   = (float*)d_out;
    float* out_idx = out_q + (size_t)n_rows * D_DIM;

    vq_kernel<<<n_rows / TPB, TPB, 0, stream>>>(x, cb, out_q, out_idx);
}

// Round 16
// 618.360 us; speedup vs baseline: 1.0119x; 1.0119x over previous
//
#include <hip/hip_runtime.h>
#include <float.h>

// VectorQuantizer: N=262144 rows of D=64 fp32, K=1024 codebook rows.
// out = [x_quantized (N*D f32) | embed_inds (N, written as f32)]
//
// Bit-exact np-fp32 semantics (verified R4): score = fmaf(-2, seq-dot,
// fadd(xnorm, enorm)); pairwise-8 norms; strict < ascending k (first-min).
//
// R16 = R15 with the register pin made compilable: clang rejects "+v" on
// float4 ("tied indirect register inputs"), so the x-row is held as 64
// NAMED SCALAR floats pinned via 4 asm statements of 16 scalar "+v" ties.
// Pinned values are asm-produced -> the allocator cannot rematerialize them
// from memory (R9/R10/R11/R14: RA otherwise reloads x per k from L1).
// cb row arrives on the SCALAR pipe (s_load_dwordx16 x4, wave-uniform);
// k-loop is pure VALU: no VMEM, no LDS except the es[k] broadcast.

typedef __attribute__((ext_vector_type(16))) float f32x16;

static constexpr int D_DIM = 64;
static constexpr int K_CB  = 1024;
static constexpr int TPB   = 256;      // 4 waves/block; grid 1024 -> 4 waves/SIMD

// ---- numpy pairwise-8 sum of squares over 16 float4s (phase A only) ----
#define NP_INIT(c0, c1)                                                     \
    float ax = __fmul_rn(c0.x, c0.x), ay = __fmul_rn(c0.y, c0.y),           \
          az = __fmul_rn(c0.z, c0.z), aw = __fmul_rn(c0.w, c0.w);           \
    float bx = __fmul_rn(c1.x, c1.x), by = __fmul_rn(c1.y, c1.y),           \
          bz = __fmul_rn(c1.z, c1.z), bw = __fmul_rn(c1.w, c1.w);
#define NP_ACC(ce, co)                                                      \
    ax = __fadd_rn(ax, __fmul_rn(ce.x, ce.x));                              \
    ay = __fadd_rn(ay, __fmul_rn(ce.y, ce.y));                              \
    az = __fadd_rn(az, __fmul_rn(ce.z, ce.z));                              \
    aw = __fadd_rn(aw, __fmul_rn(ce.w, ce.w));                              \
    bx = __fadd_rn(bx, __fmul_rn(co.x, co.x));                              \
    by = __fadd_rn(by, __fmul_rn(co.y, co.y));                              \
    bz = __fadd_rn(bz, __fmul_rn(co.z, co.z));                              \
    bw = __fadd_rn(bw, __fmul_rn(co.w, co.w));
#define NP_TREE()                                                           \
    __fadd_rn(__fadd_rn(__fadd_rn(ax, ay), __fadd_rn(az, aw)),              \
              __fadd_rn(__fadd_rn(bx, by), __fadd_rn(bz, bw)))

__device__ __forceinline__ float np_pair_sq16(
        float4 c0, float4 c1, float4 c2, float4 c3,
        float4 c4, float4 c5, float4 c6, float4 c7,
        float4 c8, float4 c9, float4 c10, float4 c11,
        float4 c12, float4 c13, float4 c14, float4 c15) {
    NP_INIT(c0, c1)
    NP_ACC(c2, c3)  NP_ACC(c4, c5)  NP_ACC(c6, c7)
    NP_ACC(c8, c9)  NP_ACC(c10, c11) NP_ACC(c12, c13) NP_ACC(c14, c15)
    return NP_TREE();
}

// ---- same pairwise-8 pattern over 64 named scalars (groups a,b,g,h) ----
// position d = 16*group + idx; r[j] accumulates d with d%8==j, i ascending.
#define SQ8_INIT(p)                                                         \
    float r0 = __fmul_rn(p##0, p##0), r1 = __fmul_rn(p##1, p##1),           \
          r2 = __fmul_rn(p##2, p##2), r3 = __fmul_rn(p##3, p##3),           \
          r4 = __fmul_rn(p##4, p##4), r5 = __fmul_rn(p##5, p##5),           \
          r6 = __fmul_rn(p##6, p##6), r7 = __fmul_rn(p##7, p##7);
#define SQ8_ACCH(p)                                                         \
    r0 = __fadd_rn(r0, __fmul_rn(p##8,  p##8));                             \
    r1 = __fadd_rn(r1, __fmul_rn(p##9,  p##9));                             \
    r2 = __fadd_rn(r2, __fmul_rn(p##10, p##10));                            \
    r3 = __fadd_rn(r3, __fmul_rn(p##11, p##11));                            \
    r4 = __fadd_rn(r4, __fmul_rn(p##12, p##12));                            \
    r5 = __fadd_rn(r5, __fmul_rn(p##13, p##13));                            \
    r6 = __fadd_rn(r6, __fmul_rn(p##14, p##14));                            \
    r7 = __fadd_rn(r7, __fmul_rn(p##15, p##15));
#define SQ8_ACCL(p)                                                         \
    r0 = __fadd_rn(r0, __fmul_rn(p##0, p##0));                              \
    r1 = __fadd_rn(r1, __fmul_rn(p##1, p##1));                              \
    r2 = __fadd_rn(r2, __fmul_rn(p##2, p##2));                              \
    r3 = __fadd_rn(r3, __fmul_rn(p##3, p##3));                              \
    r4 = __fadd_rn(r4, __fmul_rn(p##4, p##4));                              \
    r5 = __fadd_rn(r5, __fmul_rn(p##5, p##5));                              \
    r6 = __fadd_rn(r6, __fmul_rn(p##6, p##6));                              \
    r7 = __fadd_rn(r7, __fmul_rn(p##7, p##7));

// 16 steps of the d-ascending FMA chain; cb from SGPR vector sv, x scalars p.
#define FMA16(sv, p)                                                        \
    d = __fmaf_rn(sv[0],  p##0,  d); d = __fmaf_rn(sv[1],  p##1,  d);       \
    d = __fmaf_rn(sv[2],  p##2,  d); d = __fmaf_rn(sv[3],  p##3,  d);       \
    d = __fmaf_rn(sv[4],  p##4,  d); d = __fmaf_rn(sv[5],  p##5,  d);       \
    d = __fmaf_rn(sv[6],  p##6,  d); d = __fmaf_rn(sv[7],  p##7,  d);       \
    d = __fmaf_rn(sv[8],  p##8,  d); d = __fmaf_rn(sv[9],  p##9,  d);       \
    d = __fmaf_rn(sv[10], p##10, d); d = __fmaf_rn(sv[11], p##11, d);       \
    d = __fmaf_rn(sv[12], p##12, d); d = __fmaf_rn(sv[13], p##13, d);       \
    d = __fmaf_rn(sv[14], p##14, d); d = __fmaf_rn(sv[15], p##15, d);

#define PIN16(p)                                                            \
    asm volatile("" : "+v"(p##0), "+v"(p##1), "+v"(p##2), "+v"(p##3),       \
                      "+v"(p##4), "+v"(p##5), "+v"(p##6), "+v"(p##7),       \
                      "+v"(p##8), "+v"(p##9), "+v"(p##10), "+v"(p##11),     \
                      "+v"(p##12), "+v"(p##13), "+v"(p##14), "+v"(p##15));

#define UNPACK16(p, v0, v1, v2, v3)                                         \
    float p##0 = v0.x, p##1 = v0.y, p##2  = v0.z, p##3  = v0.w,             \
          p##4 = v1.x, p##5 = v1.y, p##6  = v1.z, p##7  = v1.w,             \
          p##8 = v2.x, p##9 = v2.y, p##10 = v2.z, p##11 = v2.w,             \
          p##12 = v3.x, p##13 = v3.y, p##14 = v3.z, p##15 = v3.w;

__global__ void __launch_bounds__(TPB)
__attribute__((amdgpu_waves_per_eu(4, 4)))
vq_kernel(
        const float* __restrict__ x, const float* __restrict__ cb,
        float* __restrict__ out_q, float* __restrict__ out_idx) {
    __shared__ float es[K_CB];     // 4 KB
    __shared__ int bks[TPB];       // 1 KB

    const int tid = threadIdx.x;
    const size_t row0 = (size_t)blockIdx.x * TPB;
    const size_t row  = row0 + tid;
    const float4* cb4 = reinterpret_cast<const float4*>(cb);

    // ---- phase A: block-local e-norms (numpy pairwise order) ----
#pragma unroll
    for (int j = 0; j < K_CB / TPB; ++j) {
        const int k = tid + TPB * j;
        const float4* cr = cb4 + (size_t)k * 16;
        float4 c0 = cr[0],  c1 = cr[1],  c2 = cr[2],  c3 = cr[3],
               c4 = cr[4],  c5 = cr[5],  c6 = cr[6],  c7 = cr[7],
               c8 = cr[8],  c9 = cr[9],  c10 = cr[10], c11 = cr[11],
               c12 = cr[12], c13 = cr[13], c14 = cr[14], c15 = cr[15];
        es[k] = np_pair_sq16(c0, c1, c2, c3, c4, c5, c6, c7,
                             c8, c9, c10, c11, c12, c13, c14, c15);
    }
    __syncthreads();

    // ---- phase B: my row -> 64 named scalars (4 groups); x_norm; PIN ----
    const float4* xg = reinterpret_cast<const float4*>(x + row * D_DIM);
    const float4 v0 = xg[0],  v1 = xg[1],  v2 = xg[2],  v3 = xg[3],
                 v4 = xg[4],  v5 = xg[5],  v6 = xg[6],  v7 = xg[7],
                 v8 = xg[8],  v9 = xg[9],  v10 = xg[10], v11 = xg[11],
                 v12 = xg[12], v13 = xg[13], v14 = xg[14], v15 = xg[15];
    UNPACK16(xa, v0, v1, v2, v3)      // d 0..15
    UNPACK16(xb, v4, v5, v6, v7)      // d 16..31
    UNPACK16(xg_, v8, v9, v10, v11)   // d 32..47
    UNPACK16(xh, v12, v13, v14, v15)  // d 48..63

    float xn;
    {
        SQ8_INIT(xa)      // d0..7
        SQ8_ACCH(xa)      // d8..15
        SQ8_ACCL(xb)  SQ8_ACCH(xb)      // d16..31
        SQ8_ACCL(xg_) SQ8_ACCH(xg_)     // d32..47
        SQ8_ACCL(xh)  SQ8_ACCH(xh)      // d48..63
        const float t01 = __fadd_rn(r0, r1), t23 = __fadd_rn(r2, r3);
        const float t45 = __fadd_rn(r4, r5), t67 = __fadd_rn(r6, r7);
        xn = __fadd_rn(__fadd_rn(t01, t23), __fadd_rn(t45, t67));
    }
    PIN16(xa) PIN16(xb) PIN16(xg_) PIN16(xh)

    // ---- phase C: k-scan; cb row in SGPRs (scalar pipe) ----
    float best = FLT_MAX;
    int bestk = 0;
    unsigned long long cbp = (unsigned long long)cb;   // uniform byte address
#pragma unroll 1
    for (int k = 0; k < K_CB; ++k) {
        f32x16 c0_, c1_, c2_, c3_;
        asm volatile(
            "s_load_dwordx16 %0, %4, 0x0\n\t"
            "s_load_dwordx16 %1, %4, 0x40\n\t"
            "s_load_dwordx16 %2, %4, 0x80\n\t"
            "s_load_dwordx16 %3, %4, 0xc0\n\t"
            "s_waitcnt lgkmcnt(0)"
            : "=s"(c0_), "=s"(c1_), "=s"(c2_), "=s"(c3_)
            : "s"(cbp));
        float d = 0.f;
        FMA16(c0_, xa)
        FMA16(c1_, xb)
        FMA16(c2_, xg_)
        FMA16(c3_, xh)
        const float s = __fmaf_rn(-2.f, d, __fadd_rn(xn, es[k]));
        if (s < best) { best = s; bestk = k; }   // strict < = first-min
        cbp += 4ull * D_DIM;                     // next row (scalar add)
    }

    bks[tid] = bestk;
    __syncthreads();

    // ---- phase D: coalesced gather-write of x_quantized ----
    float4* oq = reinterpret_cast<float4*>(out_q + row0 * D_DIM);
#pragma unroll
    for (int j = 0; j < 16; ++j) {
        const int f = tid + TPB * j;     // 0..4095
        const int r = f >> 4, c = f & 15;
        oq[f] = cb4[(size_t)bks[r] * 16 + c];
    }
    out_idx[row] = (float)bestk;
}

extern "C" void kernel_launch(void* const* d_in, const int* in_sizes, int n_in,
                              void* d_out, int out_size, void* d_ws, size_t ws_size,
                              hipStream_t stream) {
    const float* x  = (const float*)d_in[0];
    const float* cb = (const float*)d_in[1];
    const int n_rows = in_sizes[0] / D_DIM;     // 262144

    float* out_q   = (float*)d_out;
    float* out_idx = out_q + (size_t)n_rows * D_DIM;

    vq_kernel<<<n_rows / TPB, TPB, 0, stream>>>(x, cb, out_q, out_idx);
}

// Round 17
// 452.152 us; speedup vs baseline: 1.3838x; 1.3676x over previous
//
#include <hip/hip_runtime.h>
#include <float.h>

// VectorQuantizer: N=262144 rows of D=64 fp32, K=1024 codebook rows.
// out = [x_quantized (N*D f32) | embed_inds (N, written as f32)]
//
// Bit-exact np-fp32 semantics (verified R4): score = fmaf(-2, seq-dot,
// fadd(xnorm, enorm)); pairwise-8 norms; strict < ascending k (first-min).
//
// R17 = R11 (best: 480us; cb tiles in LDS, broadcast ds_read_b128, 2 rows/
// thread as named float4s) + ASYNC DOUBLE-BUFFERED staging: R11 staged its
// 8 cb tiles serially (barrier -> 32KB VMEM wait -> barrier; VALUBusy 62%,
// 38% idle = that stall). Now tile t+1 streams via global_load_lds (16B,
// linear dest) while tile t computes; one vmcnt(0)+barrier per tile after
// ~36K cyc of FMA has covered the latency. Prologue stage overlaps phase A/B.

typedef __attribute__((address_space(1))) const void gvoid_t;
typedef __attribute__((address_space(3))) void svoid_t;

static constexpr int D_DIM = 64;
static constexpr int K_CB  = 1024;
static constexpr int TPB   = 256;           // 4 waves
static constexpr int RPB   = 512;           // 2 rows/thread -> grid 512
static constexpr int KTILE = 128;           // cb rows per LDS tile (32 KB)
static constexpr int NKT   = K_CB / KTILE;  // 8 tiles

// numpy pairwise-8 sum of squares of 64 values held as 16 float4s.
#define NP_INIT(c0, c1)                                                     \
    float ax = __fmul_rn(c0.x, c0.x), ay = __fmul_rn(c0.y, c0.y),           \
          az = __fmul_rn(c0.z, c0.z), aw = __fmul_rn(c0.w, c0.w);           \
    float bx = __fmul_rn(c1.x, c1.x), by = __fmul_rn(c1.y, c1.y),           \
          bz = __fmul_rn(c1.z, c1.z), bw = __fmul_rn(c1.w, c1.w);
#define NP_ACC(ce, co)                                                      \
    ax = __fadd_rn(ax, __fmul_rn(ce.x, ce.x));                              \
    ay = __fadd_rn(ay, __fmul_rn(ce.y, ce.y));                              \
    az = __fadd_rn(az, __fmul_rn(ce.z, ce.z));                              \
    aw = __fadd_rn(aw, __fmul_rn(ce.w, ce.w));                              \
    bx = __fadd_rn(bx, __fmul_rn(co.x, co.x));                              \
    by = __fadd_rn(by, __fmul_rn(co.y, co.y));                              \
    bz = __fadd_rn(bz, __fmul_rn(co.z, co.z));                              \
    bw = __fadd_rn(bw, __fmul_rn(co.w, co.w));
#define NP_TREE()                                                           \
    __fadd_rn(__fadd_rn(__fadd_rn(ax, ay), __fadd_rn(az, aw)),              \
              __fadd_rn(__fadd_rn(bx, by), __fadd_rn(bz, bw)))

__device__ __forceinline__ float np_pair_sq16(
        float4 c0, float4 c1, float4 c2, float4 c3,
        float4 c4, float4 c5, float4 c6, float4 c7,
        float4 c8, float4 c9, float4 c10, float4 c11,
        float4 c12, float4 c13, float4 c14, float4 c15) {
    NP_INIT(c0, c1)
    NP_ACC(c2, c3)  NP_ACC(c4, c5)  NP_ACC(c6, c7)
    NP_ACC(c8, c9)  NP_ACC(c10, c11) NP_ACC(c12, c13) NP_ACC(c14, c15)
    return NP_TREE();
}

// One step of BOTH rows' sequential dot chains (each chain order-exact in d).
#define DOT2(i)                                                             \
    q = cr[i];                                                              \
    dA = __fmaf_rn(q.x, a##i.x, dA); dB = __fmaf_rn(q.x, b##i.x, dB);       \
    dA = __fmaf_rn(q.y, a##i.y, dA); dB = __fmaf_rn(q.y, b##i.y, dB);       \
    dA = __fmaf_rn(q.z, a##i.z, dA); dB = __fmaf_rn(q.z, b##i.z, dB);       \
    dA = __fmaf_rn(q.w, a##i.w, dA); dB = __fmaf_rn(q.w, b##i.w, dB);

__global__ void __launch_bounds__(TPB)
__attribute__((amdgpu_waves_per_eu(2, 2)))
vq_kernel(
        const float* __restrict__ x, const float* __restrict__ cb,
        float* __restrict__ out_q, float* __restrict__ out_idx) {
    __shared__ float cbt[2][KTILE * D_DIM];  // 64 KB cb tiles (double-buffered)
    __shared__ float es[K_CB];               // 4 KB
    __shared__ int   bks[RPB];               // 2 KB   total ~70 KB -> 2 blocks/CU

    const int tid = threadIdx.x;
    const size_t row0 = (size_t)blockIdx.x * RPB;
    const size_t rowA = row0 + tid;
    const size_t rowB = row0 + TPB + tid;
    const float4* cb4 = reinterpret_cast<const float4*>(cb);

    // ---- prologue: async-stage tile 0 (overlaps phases A and B) ----
#pragma unroll
    for (int j = 0; j < 8; ++j) {
        const int f = tid + TPB * j;         // float4 index; wave-contiguous
        __builtin_amdgcn_global_load_lds(
            (gvoid_t*)(cb + (size_t)f * 4),
            (svoid_t*)(&cbt[0][f * 4]), 16, 0, 0);
    }

    // ---- phase A: block-local e-norms (numpy pairwise order) ----
#pragma unroll
    for (int j = 0; j < K_CB / TPB; ++j) {
        const int k = tid + TPB * j;
        const float4* cr = cb4 + (size_t)k * 16;
        float4 c0 = cr[0],  c1 = cr[1],  c2 = cr[2],  c3 = cr[3],
               c4 = cr[4],  c5 = cr[5],  c6 = cr[6],  c7 = cr[7],
               c8 = cr[8],  c9 = cr[9],  c10 = cr[10], c11 = cr[11],
               c12 = cr[12], c13 = cr[13], c14 = cr[14], c15 = cr[15];
        es[k] = np_pair_sq16(c0, c1, c2, c3, c4, c5, c6, c7,
                             c8, c9, c10, c11, c12, c13, c14, c15);
    }

    // ---- phase B: my 2 rows in 32 NAMED float4 registers; x_norms ----
    const float4* ga = reinterpret_cast<const float4*>(x + rowA * D_DIM);
    float4 a0 = ga[0],  a1 = ga[1],  a2 = ga[2],  a3 = ga[3],
           a4 = ga[4],  a5 = ga[5],  a6 = ga[6],  a7 = ga[7],
           a8 = ga[8],  a9 = ga[9],  a10 = ga[10], a11 = ga[11],
           a12 = ga[12], a13 = ga[13], a14 = ga[14], a15 = ga[15];
    const float xnA = np_pair_sq16(a0, a1, a2, a3, a4, a5, a6, a7,
                                   a8, a9, a10, a11, a12, a13, a14, a15);
    const float4* gb = reinterpret_cast<const float4*>(x + rowB * D_DIM);
    float4 b0 = gb[0],  b1 = gb[1],  b2 = gb[2],  b3 = gb[3],
           b4 = gb[4],  b5 = gb[5],  b6 = gb[6],  b7 = gb[7],
           b8 = gb[8],  b9 = gb[9],  b10 = gb[10], b11 = gb[11],
           b12 = gb[12], b13 = gb[13], b14 = gb[14], b15 = gb[15];
    const float xnB = np_pair_sq16(b0, b1, b2, b3, b4, b5, b6, b7,
                                   b8, b9, b10, b11, b12, b13, b14, b15);

    asm volatile("s_waitcnt vmcnt(0)" ::: "memory");   // tile 0 landed
    __syncthreads();                                   // es + tile 0 visible

    // ---- phase C: k-scan over double-buffered cb tiles ----
    float bestA = FLT_MAX, bestB = FLT_MAX;
    int kA = 0, kB = 0;
    for (int t = 0; t < NKT; ++t) {
        // Issue async stage of tile t+1 into the other buffer.
        if (t + 1 < NKT) {
            const float* src = cb + (size_t)(t + 1) * KTILE * D_DIM;
            float* dst = cbt[(t + 1) & 1];
#pragma unroll
            for (int j = 0; j < 8; ++j) {
                const int f = tid + TPB * j;
                __builtin_amdgcn_global_load_lds(
                    (gvoid_t*)(src + (size_t)f * 4),
                    (svoid_t*)(&dst[f * 4]), 16, 0, 0);
            }
        }

        const float* xtc = cbt[t & 1];
#pragma unroll 2
        for (int kk = 0; kk < KTILE; ++kk) {
            const int k = t * KTILE + kk;
            const float4* cr = reinterpret_cast<const float4*>(&xtc[kk * D_DIM]);
            const float en = es[k];    // uniform broadcast read
            float dA = 0.f, dB = 0.f;
            float4 q;
            DOT2(0)  DOT2(1)  DOT2(2)  DOT2(3)
            DOT2(4)  DOT2(5)  DOT2(6)  DOT2(7)
            DOT2(8)  DOT2(9)  DOT2(10) DOT2(11)
            DOT2(12) DOT2(13) DOT2(14) DOT2(15)
            const float sA = __fmaf_rn(-2.f, dA, __fadd_rn(xnA, en));
            const float sB = __fmaf_rn(-2.f, dB, __fadd_rn(xnB, en));
            if (sA < bestA) { bestA = sA; kA = k; }   // strict < = first-min
            if (sB < bestB) { bestB = sB; kB = k; }
        }

        asm volatile("s_waitcnt vmcnt(0)" ::: "memory");  // next tile landed
        __syncthreads();                                  // publish; retire readers
    }

    bks[tid]       = kA;
    bks[TPB + tid] = kB;
    __syncthreads();

    // ---- phase D: coalesced gather-write of x_quantized (512 rows) ----
    float4* oq = reinterpret_cast<float4*>(out_q + row0 * D_DIM);
#pragma unroll
    for (int j = 0; j < RPB * 16 / TPB; ++j) {
        const int f = tid + TPB * j;     // 0..8191
        const int r = f >> 4, c = f & 15;
        oq[f] = cb4[(size_t)bks[r] * 16 + c];
    }
    out_idx[rowA] = (float)kA;
    out_idx[rowB] = (float)kB;
}

extern "C" void kernel_launch(void* const* d_in, const int* in_sizes, int n_in,
                              void* d_out, int out_size, void* d_ws, size_t ws_size,
                              hipStream_t stream) {
    const float* x  = (const float*)d_in[0];
    const float* cb = (const float*)d_in[1];
    const int n_rows = in_sizes[0] / D_DIM;     // 262144

    float* out_q   = (float*)d_out;
    float* out_idx = out_q + (size_t)n_rows * D_DIM;

    vq_kernel<<<n_rows / RPB, TPB, 0, stream>>>(x, cb, out_q, out_idx);
}